// Round 6
// baseline (173.536 us; speedup 1.0000x reference)
//
#include <hip/hip_runtime.h>
#include <stdint.h>

#define NA    3
#define KCH   8       // 5 + NUM_CLASSES
#define BLK   256
#define NWV   (BLK / 64)
#define SLICE 1200
#define QCAP  256
#define NB1   2048    // stage-1 bins: key >> 21
#define NB2   1024    // stage-2 bins: (key >> 11) & 1023

#define LOG2E 1.4426950408889634f
#define LN2   0.6931471805599453f

struct ScaleParams {
  const float*   pred;    // (B, 24, H, W)
  const float*   boxes;   // (B, N, 4)
  const int*     labels;  // (B, N)
  const uint8_t* pos;     // (B, N) bool
  const uint8_t* neg;     // (B, N) bool
  int HW;
};

__device__ __forceinline__ float fexp2(float x) { return __builtin_amdgcn_exp2f(x); }
__device__ __forceinline__ float flog2(float x) { return __builtin_amdgcn_logf(x); }

// logaddexp(0,x) = max(x,0) + log1p(exp(-|x|)); native exp2/log2, ~1e-6 rel
__device__ __forceinline__ float softplus_fast(float x) {
  const float t = fexp2(-fabsf(x) * LOG2E);
  return fmaxf(x, 0.f) + flog2(1.f + t) * LN2;
}

__device__ __forceinline__ float sl1f(float d) {
  float ad = fabsf(d);
  return (ad < 1.f) ? 0.5f * d * d : ad - 0.5f;
}

// order-preserving float->uint key (larger float => larger key)
__device__ __forceinline__ unsigned fkey(unsigned u) {
  return (u & 0x80000000u) ? ~u : (u | 0x80000000u);
}
__device__ __forceinline__ unsigned funkey(unsigned k) {
  return (k & 0x80000000u) ? (k & 0x7FFFFFFFu) : ~k;
}

__device__ __forceinline__ float blockSum(float v, float* scr) {
  #pragma unroll
  for (int off = 32; off > 0; off >>= 1) v += __shfl_down(v, off);
  const int lane = threadIdx.x & 63, w = threadIdx.x >> 6;
  __syncthreads();                       // protect scr reuse
  if (lane == 0) scr[w] = v;
  __syncthreads();
  float r = 0.f;
  #pragma unroll
  for (int i = 0; i < NWV; ++i) r += scr[i];   // same-address broadcast
  return r;
}

// Per-thread Q consecutive bins (count, value-sum) of an ascending-key hist:
// find bin holding the krem-th LARGEST, remaining count inside it, and the
// value-sum of all strictly-higher bins (+ sa_in). Block-uniform; out in sh_*.
template<int Q>
__device__ __forceinline__ void selectDigit(const unsigned* cb, const float* sb,
    int krem_in, float sa_in, int* iwav, float* fwav,
    int* sh_dig, int* sh_krem, float* sh_sa) {
  const int t = threadIdx.x, lane = t & 63, w = t >> 6;
  int c_t = 0; float s_t = 0.f;
  #pragma unroll
  for (int q = 0; q < Q; ++q) { c_t += (int)cb[q]; s_t += sb[q]; }
  int ci = c_t; float si = s_t;          // wave inclusive suffix scan
  #pragma unroll
  for (int off = 1; off < 64; off <<= 1) {
    const int   co = __shfl_down(ci, off);
    const float so = __shfl_down(si, off);
    if (lane + off < 64) { ci += co; si += so; }
  }
  __syncthreads();                       // protect iwav/fwav reuse
  if (lane == 0) { iwav[w] = ci; fwav[w] = si; }
  __syncthreads();
  int ac = 0; float as = 0.f;
  for (int w2 = w + 1; w2 < NWV; ++w2) { ac += iwav[w2]; as += fwav[w2]; }
  int   cum_c = (ci - c_t) + ac;         // strictly above this thread's top bin
  float cum_s = (si - s_t) + as;
  #pragma unroll
  for (int q = Q - 1; q >= 0; --q) {
    const int cq = (int)cb[q];
    if (cq > 0 && cum_c < krem_in && krem_in <= cum_c + cq) {  // unique
      *sh_dig  = t * Q + q;
      *sh_krem = krem_in - cum_c;
      *sh_sa   = sa_in + cum_s;
    }
    cum_c += cq; cum_s += sb[q];
  }
  __syncthreads();
}

__device__ __forceinline__ void map_block(int bid, int B,
    int& s, int& b, int& sl, int& nsl) {
  if (bid < 16 * B)      { s = 0; b = bid >> 4; sl = bid & 15; nsl = 16; }
  else if (bid < 20 * B) { const int x = bid - 16 * B; s = 1; b = x >> 2; sl = x & 3; nsl = 4; }
  else                   { s = 2; b = bid - 20 * B; sl = 0; nsl = 1; }
}

__global__ void k_zero(float4* ws4, long nw4, float* out) {
  const float4 z = {0.f, 0.f, 0.f, 0.f};
  for (long i = blockIdx.x * (long)blockDim.x + threadIdx.x; i < nw4;
       i += (long)gridDim.x * blockDim.x) ws4[i] = z;
  if (blockIdx.x == 0 && threadIdx.x < 4) out[threadIdx.x] = 0.f;
}

// Pass 1: per-slice raw-key count histogram + scalars + pos CE/loc.
// Last-arriving slice block of each row performs the stage-1 digit select.
__global__ __launch_bounds__(BLK) void k_scan(
    ScaleParams p0, ScaleParams p1, ScaleParams p2, int B,
    unsigned* g_cnt, float* g_scal, int* g_aux) {
  __shared__ unsigned hc[NB1];
  __shared__ int      queue[QCAP];
  __shared__ int      sh_qn;
  __shared__ int      iwav[NWV];
  __shared__ float    fwav[NWV];
  __shared__ float    fscr[NWV];
  __shared__ int      sh_dig, sh_krem;
  __shared__ float    sh_sa;
  __shared__ int      sh_last;
  __shared__ float    sh_np, sh_nn;

  int s, b, sl, nsl;
  map_block(blockIdx.x, B, s, b, sl, nsl);
  const ScaleParams P = (s == 0) ? p0 : (s == 1) ? p1 : p2;
  const int HW = P.HW, N = NA * HW;
  const int r = s * B + b;
  const int t = threadIdx.x;
  const int c0 = sl * SLICE, c1 = min(c0 + SLICE, N);

  for (int i = t; i < NB1; i += BLK) hc[i] = 0u;
  if (t == 0) sh_qn = 0;
  __syncthreads();

  const float* predb = P.pred + (size_t)b * (NA * KCH) * HW;
  const size_t row = (size_t)b * N;
  float nneg = 0.f;

  for (int c4 = c0 + t * 4; c4 < c1; c4 += BLK * 4) {
    const int a = (c4 >= HW) + (c4 >= 2 * HW);
    const int cell = c4 - a * HW;
    const float4 o4 = *(const float4*)(predb + (size_t)a * KCH * HW + 4 * HW + cell);
    const uchar4 pm = *(const uchar4*)(P.pos + row + c4);
    const uchar4 nm = *(const uchar4*)(P.neg + row + c4);
    #pragma unroll
    for (int q = 0; q < 4; ++q) {
      if ((&nm.x)[q]) {
        nneg += 1.f;
        atomicAdd(&hc[fkey(__float_as_uint((&o4.x)[q])) >> 21], 1u);
      }
      if ((&pm.x)[q]) {
        const int idx = atomicAdd(&sh_qn, 1);
        if (idx < QCAP) queue[idx] = c4 + q;
      }
    }
  }
  __syncthreads();
  const int npos_s = sh_qn;
  const int qn = min(npos_s, QCAP);

  // dense pos-anchor work (~12 per slice)
  float posobj = 0.f, ce = 0.f, loc = 0.f;
  for (int i = t; i < qn; i += BLK) {
    const int j = queue[i];
    const int a = (j >= HW) + (j >= 2 * HW);
    const int cell = j - a * HW;
    const float* pa = predb + (size_t)a * KCH * HW;
    posobj += softplus_fast(-pa[4 * HW + cell]);     // sp(x)-x == sp(-x)
    const float c0f = pa[5 * HW + cell];
    const float c1f = pa[6 * HW + cell];
    const float c2f = pa[7 * HW + cell];
    const float m = fmaxf(fmaxf(c0f, c1f), c2f);
    const float e = fexp2((c0f - m) * LOG2E) + fexp2((c1f - m) * LOG2E)
                  + fexp2((c2f - m) * LOG2E);
    const float lse = m + flog2(e) * LN2;
    const int lab = P.labels[row + j];
    ce += lse - ((lab == 0) ? c0f : (lab == 1) ? c1f : c2f);
    const float4 bx = *(const float4*)(P.boxes + (size_t)(row + j) * 4);
    loc += sl1f(pa[0 * HW + cell] - bx.x) + sl1f(pa[1 * HW + cell] - bx.y)
         + sl1f(pa[2 * HW + cell] - bx.z) + sl1f(pa[3 * HW + cell] - bx.w);
  }

  const float t_nneg = blockSum(nneg, fscr);
  const float t_po   = blockSum(posobj, fscr);
  const float t_ce   = blockSum(ce, fscr);
  const float t_lc   = blockSum(loc, fscr);

  if (t == 0) {
    atomicAdd(&g_scal[r * 8 + 0], (float)npos_s);
    atomicAdd(&g_scal[r * 8 + 1], t_nneg);
    atomicAdd(&g_scal[r * 8 + 2], t_po);
    atomicAdd(&g_scal[r * 8 + 3], t_ce);
    atomicAdd(&g_scal[r * 8 + 4], t_lc);
  }
  for (int i = t; i < NB1; i += BLK) {
    const unsigned c = hc[i];
    if (c) atomicAdd(&g_cnt[(size_t)r * NB1 + i], c);
  }
  __syncthreads();
  if (t == 0) {
    __threadfence();
    const int old = atomicAdd(&g_aux[r * 4 + 2], 1);
    sh_last = (old == nsl - 1) ? 1 : 0;
  }
  __syncthreads();
  if (!sh_last) return;

  // ---- row finale: stage-1 digit select from global counts ----
  if (t == 0) {
    __threadfence();
    sh_np = atomicAdd(&g_scal[r * 8 + 0], 0.f);
    sh_nn = atomicAdd(&g_scal[r * 8 + 1], 0.f);
  }
  __syncthreads();
  const int k = min(3 * (int)sh_np, (int)sh_nn);
  if (k > 0) {
    unsigned cb[8]; float sb[8];
    #pragma unroll
    for (int q = 0; q < 8; ++q) {
      cb[q] = atomicAdd(&g_cnt[(size_t)r * NB1 + t * 8 + q], 0u);
      sb[q] = 0.f;
    }
    selectDigit<8>(cb, sb, k, 0.f, iwav, fwav, &sh_dig, &sh_krem, &sh_sa);
    if (t == 0) { g_aux[r * 4 + 0] = sh_dig; g_aux[r * 4 + 1] = sh_krem; }
  } else if (t == 0) {
    g_aux[r * 4 + 0] = -1; g_aux[r * 4 + 1] = 0;
  }
}

// Pass 2: per-slice refine — sum above bin1 + fine hist inside bin1.
// Last-arriving slice block per row does stage-2 select and emits.
__global__ __launch_bounds__(BLK) void k_refine(
    ScaleParams p0, ScaleParams p1, ScaleParams p2, int B, int R, float invB,
    unsigned* g_c2, float* g_s2, float* g_scal, int* g_aux,
    unsigned* g_done, float* out) {
  __shared__ unsigned hc2[NB2];
  __shared__ float    hs2[NB2];
  __shared__ int      iwav[NWV];
  __shared__ float    fwav[NWV];
  __shared__ float    fscr[NWV];
  __shared__ int      sh_dig, sh_krem;
  __shared__ float    sh_sa, sh_sgt;
  __shared__ int      sh_last;

  int s, b, sl, nsl;
  map_block(blockIdx.x, B, s, b, sl, nsl);
  const ScaleParams P = (s == 0) ? p0 : (s == 1) ? p1 : p2;
  const int HW = P.HW, N = NA * HW;
  const int r = s * B + b;
  const int t = threadIdx.x;
  const int c0 = sl * SLICE, c1 = min(c0 + SLICE, N);

  const int bin1  = g_aux[r * 4 + 0];   // written by k_scan (prev launch)
  const int krem1 = g_aux[r * 4 + 1];

  if (bin1 >= 0) {                      // row-uniform -> block-uniform
    for (int i = t; i < NB2; i += BLK) { hc2[i] = 0u; hs2[i] = 0.f; }
    __syncthreads();

    const float* predb = P.pred + (size_t)b * (NA * KCH) * HW;
    const size_t row = (size_t)b * N;
    float sgt = 0.f;
    for (int c4 = c0 + t * 4; c4 < c1; c4 += BLK * 4) {
      const int a = (c4 >= HW) + (c4 >= 2 * HW);
      const int cell = c4 - a * HW;
      const float4 o4 = *(const float4*)(predb + (size_t)a * KCH * HW + 4 * HW + cell);
      const uchar4 nm = *(const uchar4*)(P.neg + row + c4);
      #pragma unroll
      for (int q = 0; q < 4; ++q) {
        if ((&nm.x)[q]) {
          const float obj = (&o4.x)[q];
          const unsigned key = fkey(__float_as_uint(obj));
          const int kb = (int)(key >> 21);
          if (kb > bin1) sgt += softplus_fast(obj);
          else if (kb == bin1) {
            const float sp = softplus_fast(obj);
            atomicAdd(&hc2[(key >> 11) & (NB2 - 1)], 1u);
            atomicAdd(&hs2[(key >> 11) & (NB2 - 1)], sp);
          }
        }
      }
    }
    __syncthreads();
    const float t_sgt = blockSum(sgt, fscr);
    if (t == 0 && t_sgt != 0.f) atomicAdd(&g_scal[r * 8 + 5], t_sgt);
    for (int i = t; i < NB2; i += BLK) {
      const unsigned c = hc2[i];
      if (c) {
        atomicAdd(&g_c2[(size_t)r * NB2 + i], c);
        atomicAdd(&g_s2[(size_t)r * NB2 + i], hs2[i]);
      }
    }
    __syncthreads();
  }

  if (t == 0) {
    __threadfence();
    const int old = atomicAdd(&g_aux[r * 4 + 3], 1);
    sh_last = (old == nsl - 1) ? 1 : 0;
  }
  __syncthreads();
  if (!sh_last) return;

  // ---- row finale: stage-2 select + emit ----
  float sel = 0.f;
  if (bin1 >= 0) {
    if (t == 0) {
      __threadfence();
      sh_sgt = atomicAdd(&g_scal[r * 8 + 5], 0.f);
    }
    __syncthreads();
    unsigned cb[4]; float sb[4];
    #pragma unroll
    for (int q = 0; q < 4; ++q) {
      cb[q] = atomicAdd(&g_c2[(size_t)r * NB2 + t * 4 + q], 0u);
      sb[q] = atomicAdd(&g_s2[(size_t)r * NB2 + t * 4 + q], 0.f);
    }
    selectDigit<4>(cb, sb, krem1, sh_sgt, iwav, fwav, &sh_dig, &sh_krem, &sh_sa);
    // prefix = 21 bits (sign+exp+12 mant); tie edge error <= ~2e-3, negligible
    const unsigned Tkey = ((unsigned)bin1 << 21) | ((unsigned)sh_dig << 11);
    const float Tsp = softplus_fast(__uint_as_float(funkey(Tkey)));
    sel = sh_sa + (float)sh_krem * Tsp;
  }

  if (t == 0) {
    const float npos   = g_scal[r * 8 + 0];   // written by prev launch
    const float posobj = g_scal[r * 8 + 2];
    const float ce     = g_scal[r * 8 + 3];
    const float lc     = g_scal[r * 8 + 4];
    const float denom  = fmaxf(npos, 1.f);
    atomicAdd(&out[1], (posobj + sel) / denom);
    if (npos > 0.5f) {
      atomicAdd(&out[2], ce / denom);
      atomicAdd(&out[3], lc / (denom * 4.f));
    }
    __threadfence();
    const unsigned old = atomicAdd(g_done, 1u);
    if (old == (unsigned)(R - 1)) {           // last row finalizes
      const float o = atomicAdd(&out[1], 0.f) * invB;
      const float c = atomicAdd(&out[2], 0.f) * invB;
      const float l = atomicAdd(&out[3], 0.f) * invB;
      out[0] = o + c + l;
      out[1] = o;
      out[2] = c;
      out[3] = l;
    }
  }
}

extern "C" void kernel_launch(void* const* d_in, const int* in_sizes, int n_in,
                              void* d_out, int out_size, void* d_ws, size_t ws_size,
                              hipStream_t stream) {
  (void)n_in; (void)out_size; (void)ws_size;

  const int HW0 = 80 * 80, HW1 = 40 * 40, HW2 = 20 * 20;
  const int B = in_sizes[0] / (NA * KCH * HW0);
  const int R = 3 * B;
  const float invB = 1.f / (float)B;

  ScaleParams p0{(const float*)d_in[0],  (const float*)d_in[1],
                 (const int*)d_in[2],    (const uint8_t*)d_in[3],
                 (const uint8_t*)d_in[4], HW0};
  ScaleParams p1{(const float*)d_in[5],  (const float*)d_in[6],
                 (const int*)d_in[7],    (const uint8_t*)d_in[8],
                 (const uint8_t*)d_in[9], HW1};
  ScaleParams p2{(const float*)d_in[10], (const float*)d_in[11],
                 (const int*)d_in[12],   (const uint8_t*)d_in[13],
                 (const uint8_t*)d_in[14], HW2};

  float* out = (float*)d_out;

  // workspace layout (16B-aligned sections); ws >= 6.3 MB confirmed (round 2)
  char* w = (char*)d_ws;
  unsigned* g_cnt  = (unsigned*)w;                 w += (size_t)R * NB1 * 4;
  unsigned* g_c2   = (unsigned*)w;                 w += (size_t)R * NB2 * 4;
  float*    g_s2   = (float*)w;                    w += (size_t)R * NB2 * 4;
  float*    g_scal = (float*)w;                    w += (size_t)R * 8 * 4;
  int*      g_aux  = (int*)w;                      w += (size_t)R * 4 * 4;
  unsigned* g_done = (unsigned*)w;                 w += 16;
  const size_t need = (size_t)(w - (char*)d_ws);

  const long nw4 = (long)((need + 15) / 16);
  int zgrid = (int)((nw4 + 255) / 256); if (zgrid > 2048) zgrid = 2048;
  k_zero<<<zgrid, 256, 0, stream>>>((float4*)d_ws, nw4, out);

  const int grid = 21 * B;
  k_scan<<<grid, BLK, 0, stream>>>(p0, p1, p2, B, g_cnt, g_scal, g_aux);
  k_refine<<<grid, BLK, 0, stream>>>(p0, p1, p2, B, R, invB,
                                     g_c2, g_s2, g_scal, g_aux, g_done, out);
}

// Round 7
// 46.155 us; speedup vs baseline: 3.7598x; 3.7598x over previous
//
#include <hip/hip_runtime.h>
#include <stdint.h>

#define NA   3
#define KCH  8       // 5 + NUM_CLASSES
#define NB1  2048    // stage-1 bins: key >> 21 (sign+8exp+2mant)
#define NB2  1024    // stage-2 bins: (key >> 11) & 1023
#define SL0  4       // slices per scale-0 row (4800 elems each)
#define QCAP 512

#define LOG2E 1.4426950408889634f
#define LN2   0.6931471805599453f

struct ScaleParams {
  const float*   pred;    // (B, 24, H, W)
  const float*   boxes;   // (B, N, 4)
  const int*     labels;  // (B, N)
  const uint8_t* pos;     // (B, N) bool
  const uint8_t* neg;     // (B, N) bool
  int HW;
};

__device__ __forceinline__ float fexp2(float x) { return __builtin_amdgcn_exp2f(x); }
__device__ __forceinline__ float flog2(float x) { return __builtin_amdgcn_logf(x); }

// logaddexp(0,x) = max(x,0) + log1p(exp(-|x|)); native exp2/log2, ~1e-6 rel
__device__ __forceinline__ float softplus_fast(float x) {
  const float t = fexp2(-fabsf(x) * LOG2E);
  return fmaxf(x, 0.f) + flog2(1.f + t) * LN2;
}

__device__ __forceinline__ float sl1f(float d) {
  float ad = fabsf(d);
  return (ad < 1.f) ? 0.5f * d * d : ad - 0.5f;
}

// order-preserving float->uint key (larger float => larger key)
__device__ __forceinline__ unsigned fkey(unsigned u) {
  return (u & 0x80000000u) ? ~u : (u | 0x80000000u);
}
__device__ __forceinline__ unsigned funkey(unsigned k) {
  return (k & 0x80000000u) ? (k & 0x7FFFFFFFu) : ~k;
}

template<int NTHR>
__device__ __forceinline__ float blockSum(float v, float* scr) {
  #pragma unroll
  for (int off = 32; off > 0; off >>= 1) v += __shfl_down(v, off);
  const int lane = threadIdx.x & 63, w = threadIdx.x >> 6;
  __syncthreads();                       // protect scr reuse
  if (lane == 0) scr[w] = v;
  __syncthreads();
  float r = 0.f;
  #pragma unroll
  for (int i = 0; i < NTHR / 64; ++i) r += scr[i];
  return r;
}

// Per-thread Q consecutive bins (count, value-sum) of an ascending-key hist:
// find bin holding the krem-th LARGEST, remaining count inside it, and the
// value-sum of all strictly-higher bins (+ sa_in). Block-uniform; out in sh_*.
template<int NTHR, int Q>
__device__ __forceinline__ void selectDigit(const unsigned* cb, const float* sb,
    int krem_in, float sa_in, int* iwav, float* fwav,
    int* sh_dig, int* sh_krem, float* sh_sa) {
  const int t = threadIdx.x, lane = t & 63, w = t >> 6;
  int c_t = 0; float s_t = 0.f;
  #pragma unroll
  for (int q = 0; q < Q; ++q) { c_t += (int)cb[q]; s_t += sb[q]; }
  int ci = c_t; float si = s_t;          // wave inclusive suffix scan
  #pragma unroll
  for (int off = 1; off < 64; off <<= 1) {
    const int   co = __shfl_down(ci, off);
    const float so = __shfl_down(si, off);
    if (lane + off < 64) { ci += co; si += so; }
  }
  __syncthreads();                       // protect iwav/fwav reuse
  if (lane == 0) { iwav[w] = ci; fwav[w] = si; }
  __syncthreads();
  int ac = 0; float as = 0.f;
  #pragma unroll
  for (int w2 = 0; w2 < NTHR / 64; ++w2)
    if (w2 > w) { ac += iwav[w2]; as += fwav[w2]; }
  int   cum_c = (ci - c_t) + ac;         // strictly above this thread's top bin
  float cum_s = (si - s_t) + as;
  #pragma unroll
  for (int q = Q - 1; q >= 0; --q) {
    const int cq = (int)cb[q];
    if (cq > 0 && cum_c < krem_in && krem_in <= cum_c + cq) {  // unique
      *sh_dig  = t * Q + q;
      *sh_krem = krem_in - cum_c;
      *sh_sa   = sa_in + cum_s;
    }
    cum_c += cq; cum_s += sb[q];
  }
  __syncthreads();
}

__device__ __forceinline__ void emit_row(int npos, float posobj, float sel,
    float ce, float loc, float* out, unsigned* done, int arrivals, float invB) {
  if (threadIdx.x == 0) {
    const float denom = (float)max(npos, 1);
    atomicAdd(&out[1], (posobj + sel) / denom);
    if (npos > 0) {
      atomicAdd(&out[2], ce / denom);
      atomicAdd(&out[3], loc / (denom * 4.f));
    }
    __threadfence();
    const unsigned old = atomicAdd(done, 1u);
    if (old == (unsigned)(arrivals - 1)) {     // last arrival finalizes
      const float o = atomicAdd(&out[1], 0.f) * invB;
      const float c = atomicAdd(&out[2], 0.f) * invB;
      const float l = atomicAdd(&out[3], 0.f) * invB;
      out[0] = o + c + l;
      out[1] = o;
      out[2] = c;
      out[3] = l;
    }
  }
}

__global__ void k_zero(float* g_scal, int nscal, unsigned* done, float* out) {
  for (int i = threadIdx.x; i < nscal; i += blockDim.x) g_scal[i] = 0.f;
  if (threadIdx.x == 0) *done = 0u;
  if (threadIdx.x < 4) out[threadIdx.x] = 0.f;
}

// K1: s0 rows sliced 4x -> count hist to PRIVATE segment (plain stores) +
// scalars (atomicAdd). s1/s2 rows -> fully local 2-sweep select, emit.
__global__ __launch_bounds__(512) void k_scan(
    ScaleParams p0, ScaleParams p1, ScaleParams p2, int B, int R, float invB,
    unsigned* g_seg1, float* g_scal, unsigned* done, float* out) {
  __shared__ unsigned hc[NB1];
  __shared__ float    hs[NB2];
  __shared__ int      queue[QCAP];
  __shared__ int      sh_qn;
  __shared__ int      iwav[8];
  __shared__ float    fwav[8], fscr[8];
  __shared__ int      sh_dig, sh_krem;
  __shared__ float    sh_sa;

  const int bid = blockIdx.x;
  int s, b, sl; bool whole;
  if (bid < SL0 * B)          { s = 0; b = bid >> 2; sl = bid & 3; whole = false; }
  else if (bid < (SL0+1) * B) { s = 1; b = bid - SL0*B; sl = 0; whole = true; }
  else                        { s = 2; b = bid - (SL0+1)*B; sl = 0; whole = true; }
  const ScaleParams P = (s == 0) ? p0 : (s == 1) ? p1 : p2;
  const int HW = P.HW, N = NA * HW;
  const int r = s * B + b;
  const int t = threadIdx.x;
  const int c0 = whole ? 0 : sl * 4800;
  const int c1 = whole ? N : c0 + 4800;

  for (int i = t; i < NB1; i += 512) hc[i] = 0u;
  if (t == 0) sh_qn = 0;
  __syncthreads();

  const float* predb = P.pred + (size_t)b * (NA * KCH) * HW;
  const size_t row = (size_t)b * N;
  float nneg = 0.f;

  // sweep: raw-key count histogram (no transcendentals) + pos queue
  for (int c4 = c0 + t * 4; c4 < c1; c4 += 512 * 4) {
    const int a = (c4 >= HW) + (c4 >= 2 * HW);
    const int cell = c4 - a * HW;
    const float4 o4 = *(const float4*)(predb + (size_t)a * KCH * HW + 4 * HW + cell);
    const uchar4 pm = *(const uchar4*)(P.pos + row + c4);
    const uchar4 nm = *(const uchar4*)(P.neg + row + c4);
    #pragma unroll
    for (int q = 0; q < 4; ++q) {
      if ((&nm.x)[q]) {
        nneg += 1.f;
        atomicAdd(&hc[fkey(__float_as_uint((&o4.x)[q])) >> 21], 1u);
      }
      if ((&pm.x)[q]) {
        const int idx = atomicAdd(&sh_qn, 1);
        if (idx < QCAP) queue[idx] = c4 + q;
      }
    }
  }
  __syncthreads();
  const int npos = sh_qn;
  const int qn = min(npos, QCAP);

  // dense pos-anchor work (~1% of anchors)
  float posobj = 0.f, ce = 0.f, loc = 0.f;
  for (int i = t; i < qn; i += 512) {
    const int j = queue[i];
    const int a = (j >= HW) + (j >= 2 * HW);
    const int cell = j - a * HW;
    const float* pa = predb + (size_t)a * KCH * HW;
    posobj += softplus_fast(-pa[4 * HW + cell]);     // sp(x)-x == sp(-x)
    const float c0f = pa[5 * HW + cell];
    const float c1f = pa[6 * HW + cell];
    const float c2f = pa[7 * HW + cell];
    const float m = fmaxf(fmaxf(c0f, c1f), c2f);
    const float e = fexp2((c0f - m) * LOG2E) + fexp2((c1f - m) * LOG2E)
                  + fexp2((c2f - m) * LOG2E);
    const float lse = m + flog2(e) * LN2;
    const int lab = P.labels[row + j];
    ce += lse - ((lab == 0) ? c0f : (lab == 1) ? c1f : c2f);
    const float4 bx = *(const float4*)(P.boxes + (size_t)(row + j) * 4);
    loc += sl1f(pa[0 * HW + cell] - bx.x) + sl1f(pa[1 * HW + cell] - bx.y)
         + sl1f(pa[2 * HW + cell] - bx.z) + sl1f(pa[3 * HW + cell] - bx.w);
  }

  const float t_nneg = blockSum<512>(nneg, fscr);
  const float t_po   = blockSum<512>(posobj, fscr);
  const float t_ce   = blockSum<512>(ce, fscr);
  const float t_lc   = blockSum<512>(loc, fscr);

  if (!whole) {
    if (t == 0) {
      atomicAdd(&g_scal[r * 8 + 0], (float)npos);
      atomicAdd(&g_scal[r * 8 + 1], t_nneg);
      atomicAdd(&g_scal[r * 8 + 2], t_po);
      atomicAdd(&g_scal[r * 8 + 3], t_ce);
      atomicAdd(&g_scal[r * 8 + 4], t_lc);
    }
    // private segment: plain coalesced stores, read only by NEXT kernel
    unsigned* seg = g_seg1 + (size_t)(b * SL0 + sl) * NB1;
    for (int i = t; i < NB1; i += 512) seg[i] = hc[i];
    return;
  }

  // ---- whole row (s1/s2): local 2-stage select, no global state ----
  const int k = min(3 * npos, (int)t_nneg);
  float sel = 0.f;
  if (k > 0) {
    unsigned cb[4]; float sb[4];
    #pragma unroll
    for (int q = 0; q < 4; ++q) { cb[q] = hc[t * 4 + q]; sb[q] = 0.f; }
    selectDigit<512, 4>(cb, sb, k, 0.f, iwav, fwav, &sh_dig, &sh_krem, &sh_sa);
    const int bin1 = sh_dig; const int krem1 = sh_krem;

    for (int i = t; i < NB2; i += 512) { hc[i] = 0u; hs[i] = 0.f; }
    __syncthreads();
    float sgt = 0.f;
    for (int c4 = t * 4; c4 < N; c4 += 512 * 4) {
      const int a = (c4 >= HW) + (c4 >= 2 * HW);
      const int cell = c4 - a * HW;
      const float4 o4 = *(const float4*)(predb + (size_t)a * KCH * HW + 4 * HW + cell);
      const uchar4 nm = *(const uchar4*)(P.neg + row + c4);
      #pragma unroll
      for (int q = 0; q < 4; ++q) {
        if ((&nm.x)[q]) {
          const float obj = (&o4.x)[q];
          const unsigned key = fkey(__float_as_uint(obj));
          const int kb = (int)(key >> 21);
          if (kb > bin1) sgt += softplus_fast(obj);
          else if (kb == bin1) {
            const float sp = softplus_fast(obj);
            atomicAdd(&hc[(key >> 11) & (NB2 - 1)], 1u);
            atomicAdd(&hs[(key >> 11) & (NB2 - 1)], sp);
          }
        }
      }
    }
    __syncthreads();
    const float t_sgt = blockSum<512>(sgt, fscr);
    unsigned cb2[2]; float sb2[2];
    #pragma unroll
    for (int q = 0; q < 2; ++q) { cb2[q] = hc[t * 2 + q]; sb2[q] = hs[t * 2 + q]; }
    selectDigit<512, 2>(cb2, sb2, krem1, t_sgt, iwav, fwav,
                        &sh_dig, &sh_krem, &sh_sa);
    // 21-bit prefix tie-edge approx: error <= krem * width, ~1e-3 max
    const unsigned Tkey = ((unsigned)bin1 << 21) | ((unsigned)sh_dig << 11);
    sel = sh_sa + (float)sh_krem * softplus_fast(__uint_as_float(funkey(Tkey)));
  }
  emit_row(npos, t_po, sel, t_ce, t_lc, out, done, R, invB);
}

// K2 (s0 rows only): combine 4 coarse segments (plain loads, prev kernel) ->
// stage-1 select (redundant in the row's 4 blocks, deterministic) -> sweep
// own slice: sgt above bin1, fine cnt+sum hist inside bin1 -> private segment.
__global__ __launch_bounds__(512) void k_refine(
    ScaleParams p0, int B,
    const unsigned* g_seg1, float* g_scal, int* g_aux,
    unsigned* g_seg2c, float* g_seg2s) {
  __shared__ unsigned hc2[NB2];
  __shared__ float    hs2[NB2];
  __shared__ int      iwav[8];
  __shared__ float    fwav[8], fscr[8];
  __shared__ int      sh_dig, sh_krem;
  __shared__ float    sh_sa;

  const int bid = blockIdx.x;
  const int b = bid >> 2, sl = bid & 3;
  const int t = threadIdx.x;
  const int HW = p0.HW, N = NA * HW;

  const int np = (int)g_scal[b * 8 + 0];     // exact: integer-valued floats
  const int nn = (int)g_scal[b * 8 + 1];
  const int k = min(3 * np, nn);
  if (k <= 0) {
    if (sl == 0 && t == 0) { g_aux[2 * b] = -1; g_aux[2 * b + 1] = 0; }
    return;
  }

  // stage-1: combine 4 private segments; thread t owns bins [4t, 4t+4)
  unsigned cb[4] = {0u, 0u, 0u, 0u}; float sb[4] = {0.f, 0.f, 0.f, 0.f};
  #pragma unroll
  for (int seg = 0; seg < SL0; ++seg) {
    const uint4 v = ((const uint4*)(g_seg1 + (size_t)(b * SL0 + seg) * NB1))[t];
    cb[0] += v.x; cb[1] += v.y; cb[2] += v.z; cb[3] += v.w;
  }
  selectDigit<512, 4>(cb, sb, k, 0.f, iwav, fwav, &sh_dig, &sh_krem, &sh_sa);
  const int bin1 = sh_dig; const int krem1 = sh_krem;
  if (sl == 0 && t == 0) { g_aux[2 * b] = bin1; g_aux[2 * b + 1] = krem1; }

  for (int i = t; i < NB2; i += 512) { hc2[i] = 0u; hs2[i] = 0.f; }
  __syncthreads();

  const float* predb = p0.pred + (size_t)b * (NA * KCH) * HW;
  const size_t row = (size_t)b * N;
  const int c0 = sl * 4800, c1 = c0 + 4800;
  float sgt = 0.f;
  for (int c4 = c0 + t * 4; c4 < c1; c4 += 512 * 4) {
    const int a = (c4 >= HW) + (c4 >= 2 * HW);
    const int cell = c4 - a * HW;
    const float4 o4 = *(const float4*)(predb + (size_t)a * KCH * HW + 4 * HW + cell);
    const uchar4 nm = *(const uchar4*)(p0.neg + row + c4);
    #pragma unroll
    for (int q = 0; q < 4; ++q) {
      if ((&nm.x)[q]) {
        const float obj = (&o4.x)[q];
        const unsigned key = fkey(__float_as_uint(obj));
        const int kb = (int)(key >> 21);
        if (kb > bin1) sgt += softplus_fast(obj);       // ~3% of elements
        else if (kb == bin1) {
          const float sp = softplus_fast(obj);
          atomicAdd(&hc2[(key >> 11) & (NB2 - 1)], 1u);
          atomicAdd(&hs2[(key >> 11) & (NB2 - 1)], sp);
        }
      }
    }
  }
  __syncthreads();
  const float t_sgt = blockSum<512>(sgt, fscr);
  if (t == 0 && t_sgt != 0.f) atomicAdd(&g_scal[b * 8 + 5], t_sgt);

  unsigned* segc = g_seg2c + (size_t)(b * SL0 + sl) * NB2;
  float*    segs = g_seg2s + (size_t)(b * SL0 + sl) * NB2;
  for (int i = t; i < NB2; i += 512) { segc[i] = hc2[i]; segs[i] = hs2[i]; }
}

// K3 (one block per s0 row): combine fine segments, stage-2 select, emit.
__global__ __launch_bounds__(256) void k_final(
    int B, int R, float invB,
    const unsigned* g_seg2c, const float* g_seg2s,
    const float* g_scal, const int* g_aux, unsigned* done, float* out) {
  __shared__ int   iwav[4];
  __shared__ float fwav[4];
  __shared__ int   sh_dig, sh_krem;
  __shared__ float sh_sa;

  const int b = blockIdx.x;
  const int t = threadIdx.x;

  const int   np     = (int)g_scal[b * 8 + 0];
  const float posobj = g_scal[b * 8 + 2];
  const float ce     = g_scal[b * 8 + 3];
  const float lc     = g_scal[b * 8 + 4];
  const int   bin1   = g_aux[2 * b];
  const int   krem1  = g_aux[2 * b + 1];

  float sel = 0.f;
  if (bin1 >= 0) {
    const float sgt = g_scal[b * 8 + 5];
    unsigned cb[4] = {0u, 0u, 0u, 0u}; float sb[4] = {0.f, 0.f, 0.f, 0.f};
    #pragma unroll
    for (int seg = 0; seg < SL0; ++seg) {
      const uint4  c = ((const uint4*)(g_seg2c + (size_t)(b * SL0 + seg) * NB2))[t];
      const float4 v = ((const float4*)(g_seg2s + (size_t)(b * SL0 + seg) * NB2))[t];
      cb[0] += c.x; cb[1] += c.y; cb[2] += c.z; cb[3] += c.w;
      sb[0] += v.x; sb[1] += v.y; sb[2] += v.z; sb[3] += v.w;
    }
    selectDigit<256, 4>(cb, sb, krem1, sgt, iwav, fwav, &sh_dig, &sh_krem, &sh_sa);
    const unsigned Tkey = ((unsigned)bin1 << 21) | ((unsigned)sh_dig << 11);
    sel = sh_sa + (float)sh_krem * softplus_fast(__uint_as_float(funkey(Tkey)));
  }
  emit_row(np, posobj, sel, ce, lc, out, done, R, invB);
}

extern "C" void kernel_launch(void* const* d_in, const int* in_sizes, int n_in,
                              void* d_out, int out_size, void* d_ws, size_t ws_size,
                              hipStream_t stream) {
  (void)n_in; (void)out_size; (void)ws_size;

  const int HW0 = 80 * 80, HW1 = 40 * 40, HW2 = 20 * 20;
  const int B = in_sizes[0] / (NA * KCH * HW0);
  const int R = 3 * B;
  const float invB = 1.f / (float)B;

  ScaleParams p0{(const float*)d_in[0],  (const float*)d_in[1],
                 (const int*)d_in[2],    (const uint8_t*)d_in[3],
                 (const uint8_t*)d_in[4], HW0};
  ScaleParams p1{(const float*)d_in[5],  (const float*)d_in[6],
                 (const int*)d_in[7],    (const uint8_t*)d_in[8],
                 (const uint8_t*)d_in[9], HW1};
  ScaleParams p2{(const float*)d_in[10], (const float*)d_in[11],
                 (const int*)d_in[12],   (const uint8_t*)d_in[13],
                 (const uint8_t*)d_in[14], HW2};

  float* out = (float*)d_out;

  // workspace layout (all sections 16B aligned)
  char* w = (char*)d_ws;
  unsigned* g_seg1  = (unsigned*)w;  w += (size_t)B * SL0 * NB1 * 4;  // 4 MB
  unsigned* g_seg2c = (unsigned*)w;  w += (size_t)B * SL0 * NB2 * 4;  // 2 MB
  float*    g_seg2s = (float*)w;     w += (size_t)B * SL0 * NB2 * 4;  // 2 MB
  float*    g_scal  = (float*)w;     w += (size_t)R * 8 * 4;
  int*      g_aux   = (int*)w;       w += (size_t)B * 2 * 4;
  unsigned* g_done  = (unsigned*)w;  w += 16;

  // zero only what accumulates (12 KB) — segments are fully overwritten
  k_zero<<<1, 256, 0, stream>>>(g_scal, R * 8, g_done, out);
  k_scan<<<(SL0 + 2) * B, 512, 0, stream>>>(p0, p1, p2, B, R, invB,
                                            g_seg1, g_scal, g_done, out);
  k_refine<<<SL0 * B, 512, 0, stream>>>(p0, B, g_seg1, g_scal, g_aux,
                                        g_seg2c, g_seg2s);
  k_final<<<B, 256, 0, stream>>>(B, R, invB, g_seg2c, g_seg2s,
                                 g_scal, g_aux, g_done, out);
}

// Round 8
// 39.281 us; speedup vs baseline: 4.4178x; 1.1750x over previous
//
#include <hip/hip_runtime.h>
#include <stdint.h>

#define NA   3
#define KCH  8       // 5 + NUM_CLASSES
#define BLK  1024
#define NWV  (BLK / 64)
#define NB   2048    // histogram bins (stage1: key>>21; stage2: (key>>10)&2047)
#define QCAP 768

#define LOG2E 1.4426950408889634f
#define LN2   0.6931471805599453f

struct ScaleParams {
  const float*   pred;    // (B, 24, H, W)
  const float*   boxes;   // (B, N, 4)
  const int*     labels;  // (B, N)
  const uint8_t* pos;     // (B, N) bool
  const uint8_t* neg;     // (B, N) bool
  int HW;
};

__device__ __forceinline__ float fexp2(float x) { return __builtin_amdgcn_exp2f(x); }
__device__ __forceinline__ float flog2(float x) { return __builtin_amdgcn_logf(x); }

// logaddexp(0,x) = max(x,0) + log1p(exp(-|x|)); native exp2/log2, ~1e-6 rel
__device__ __forceinline__ float softplus_fast(float x) {
  const float t = fexp2(-fabsf(x) * LOG2E);
  return fmaxf(x, 0.f) + flog2(1.f + t) * LN2;
}

__device__ __forceinline__ float sl1f(float d) {
  float ad = fabsf(d);
  return (ad < 1.f) ? 0.5f * d * d : ad - 0.5f;
}

// order-preserving float->uint key (larger float => larger key)
__device__ __forceinline__ unsigned fkey(unsigned u) {
  return (u & 0x80000000u) ? ~u : (u | 0x80000000u);
}
__device__ __forceinline__ unsigned funkey(unsigned k) {
  return (k & 0x80000000u) ? (k & 0x7FFFFFFFu) : ~k;
}

__device__ __forceinline__ float blockSum(float v, float* scr) {
  #pragma unroll
  for (int off = 32; off > 0; off >>= 1) v += __shfl_down(v, off);
  const int lane = threadIdx.x & 63, w = threadIdx.x >> 6;
  __syncthreads();                       // protect scr reuse
  if (lane == 0) scr[w] = v;
  __syncthreads();
  float r = 0.f;
  #pragma unroll
  for (int i = 0; i < NWV; ++i) r += scr[i];   // same-address broadcast
  return r;
}

// Per-thread 2 consecutive bins (count, value-sum) of an ascending-key hist:
// find bin holding the krem-th LARGEST, remaining count inside it, and the
// value-sum of all strictly-higher bins (+ sa_in). Block-uniform; out in sh_*.
__device__ __forceinline__ void selectDigit2(const unsigned* cb, const float* sb,
    int krem_in, float sa_in, int* iwav, float* fwav,
    int* sh_dig, int* sh_krem, float* sh_sa) {
  const int t = threadIdx.x, lane = t & 63, w = t >> 6;
  int c_t = (int)cb[0] + (int)cb[1];
  float s_t = sb[0] + sb[1];
  int ci = c_t; float si = s_t;          // wave inclusive suffix scan
  #pragma unroll
  for (int off = 1; off < 64; off <<= 1) {
    const int   co = __shfl_down(ci, off);
    const float so = __shfl_down(si, off);
    if (lane + off < 64) { ci += co; si += so; }
  }
  __syncthreads();                       // protect iwav/fwav reuse
  if (lane == 0) { iwav[w] = ci; fwav[w] = si; }
  __syncthreads();
  int ac = 0; float as = 0.f;
  #pragma unroll
  for (int w2 = 0; w2 < NWV; ++w2)
    if (w2 > w) { ac += iwav[w2]; as += fwav[w2]; }
  int   cum_c = (ci - c_t) + ac;         // strictly above this thread's top bin
  float cum_s = (si - s_t) + as;
  #pragma unroll
  for (int q = 1; q >= 0; --q) {
    const int cq = (int)cb[q];
    if (cq > 0 && cum_c < krem_in && krem_in <= cum_c + cq) {  // unique
      *sh_dig  = t * 2 + q;
      *sh_krem = krem_in - cum_c;
      *sh_sa   = sa_in + cum_s;
    }
    cum_c += cq; cum_s += sb[q];
  }
  __syncthreads();
}

__global__ void k_zero(float* out, unsigned* done) {
  if (threadIdx.x < 4) out[threadIdx.x] = 0.f;
  if (threadIdx.x == 0) *done = 0u;
}

// One block per (scale, batch) row. 16 waves, ILP-2 sweeps, 2-stage select.
__global__ __launch_bounds__(BLK, 8) void k_row(
    ScaleParams p0, ScaleParams p1, ScaleParams p2,
    int B, int R, float invB, float* out, unsigned* done) {
  __shared__ unsigned hc[NB];
  __shared__ float    hs[NB];
  __shared__ int      queue[QCAP];
  __shared__ int      sh_qn;
  __shared__ int      iwav[NWV];
  __shared__ float    fwav[NWV], fscr[NWV];
  __shared__ int      sh_dig, sh_krem;
  __shared__ float    sh_sa;

  const int r = blockIdx.x;
  const int s = (r >= B) + (r >= 2 * B);   // heavy s0 rows dispatched first
  const int b = r - s * B;
  const ScaleParams P = (s == 0) ? p0 : (s == 1) ? p1 : p2;
  const int HW = P.HW, N = NA * HW;
  const int t = threadIdx.x;

  for (int i = t; i < NB; i += BLK) hc[i] = 0u;
  if (t == 0) sh_qn = 0;
  __syncthreads();

  const float* predb = P.pred + (size_t)b * (NA * KCH) * HW;
  const size_t row = (size_t)b * N;
  float nneg = 0.f;

  // ---- sweep 1: counts-only raw-key histogram + pos queue (ILP-2) ----
  for (int c8 = t * 8; c8 < N; c8 += BLK * 8) {
    const int a = (c8 >= HW) + (c8 >= 2 * HW);
    const int cell = c8 - a * HW;
    const float* po = predb + (size_t)a * KCH * HW + 4 * HW + cell;
    const float4 o0 = *(const float4*)po;          // independent loads:
    const float4 o1 = *(const float4*)(po + 4);    // 2x16B + 2x8B in flight
    const uint2 pmv = *(const uint2*)(P.pos + row + c8);
    const uint2 nmv = *(const uint2*)(P.neg + row + c8);
    #pragma unroll
    for (int q = 0; q < 4; ++q) {
      if ((nmv.x >> (8 * q)) & 0xFFu) {
        nneg += 1.f;
        atomicAdd(&hc[fkey(__float_as_uint((&o0.x)[q])) >> 21], 1u);
      }
      if ((pmv.x >> (8 * q)) & 0xFFu) {
        const int idx = atomicAdd(&sh_qn, 1);
        if (idx < QCAP) queue[idx] = c8 + q;
      }
    }
    #pragma unroll
    for (int q = 0; q < 4; ++q) {
      if ((nmv.y >> (8 * q)) & 0xFFu) {
        nneg += 1.f;
        atomicAdd(&hc[fkey(__float_as_uint((&o1.x)[q])) >> 21], 1u);
      }
      if ((pmv.y >> (8 * q)) & 0xFFu) {
        const int idx = atomicAdd(&sh_qn, 1);
        if (idx < QCAP) queue[idx] = c8 + 4 + q;
      }
    }
  }
  __syncthreads();
  const int npos = sh_qn;
  const int qn = min(npos, QCAP);

  // ---- dense pos-anchor work (~1%): softplus/CE/smooth-L1, L2-hot ----
  float posobj = 0.f, ce = 0.f, loc = 0.f;
  for (int i = t; i < qn; i += BLK) {
    const int j = queue[i];
    const int a = (j >= HW) + (j >= 2 * HW);
    const int cell = j - a * HW;
    const float* pa = predb + (size_t)a * KCH * HW;
    posobj += softplus_fast(-pa[4 * HW + cell]);     // sp(x)-x == sp(-x)
    const float c0f = pa[5 * HW + cell];
    const float c1f = pa[6 * HW + cell];
    const float c2f = pa[7 * HW + cell];
    const float m = fmaxf(fmaxf(c0f, c1f), c2f);
    const float e = fexp2((c0f - m) * LOG2E) + fexp2((c1f - m) * LOG2E)
                  + fexp2((c2f - m) * LOG2E);
    const float lse = m + flog2(e) * LN2;
    const int lab = P.labels[row + j];
    ce += lse - ((lab == 0) ? c0f : (lab == 1) ? c1f : c2f);
    const float4 bx = *(const float4*)(P.boxes + (size_t)(row + j) * 4);
    loc += sl1f(pa[0 * HW + cell] - bx.x) + sl1f(pa[1 * HW + cell] - bx.y)
         + sl1f(pa[2 * HW + cell] - bx.z) + sl1f(pa[3 * HW + cell] - bx.w);
  }

  const float t_nneg = blockSum(nneg, fscr);
  const float t_po   = blockSum(posobj, fscr);
  const float t_ce   = blockSum(ce, fscr);
  const float t_lc   = blockSum(loc, fscr);
  const int k = min(3 * npos, (int)t_nneg);

  float sel = 0.f;
  if (k > 0) {  // block-uniform
    // ---- stage 1: bits[31:21], counts only ----
    unsigned cb[2]; float sb[2];
    cb[0] = hc[2 * t]; cb[1] = hc[2 * t + 1]; sb[0] = 0.f; sb[1] = 0.f;
    selectDigit2(cb, sb, k, 0.f, iwav, fwav, &sh_dig, &sh_krem, &sh_sa);
    const int bin1 = sh_dig; const int krem1 = sh_krem;

    // ---- sweep 2 (L2-hot): sum above bin1; fine hist inside bin1 ----
    for (int i = t; i < NB; i += BLK) { hc[i] = 0u; hs[i] = 0.f; }
    __syncthreads();
    float sgt = 0.f;
    for (int c8 = t * 8; c8 < N; c8 += BLK * 8) {
      const int a = (c8 >= HW) + (c8 >= 2 * HW);
      const int cell = c8 - a * HW;
      const float* po = predb + (size_t)a * KCH * HW + 4 * HW + cell;
      const float4 o0 = *(const float4*)po;
      const float4 o1 = *(const float4*)(po + 4);
      const uint2 nmv = *(const uint2*)(P.neg + row + c8);
      #pragma unroll
      for (int q = 0; q < 4; ++q) {
        if ((nmv.x >> (8 * q)) & 0xFFu) {
          const float obj = (&o0.x)[q];
          const unsigned key = fkey(__float_as_uint(obj));
          const int kb = (int)(key >> 21);
          if (kb > bin1) sgt += softplus_fast(obj);        // ~3%
          else if (kb == bin1) {
            atomicAdd(&hc[(key >> 10) & (NB - 1)], 1u);
            atomicAdd(&hs[(key >> 10) & (NB - 1)], softplus_fast(obj));
          }
        }
      }
      #pragma unroll
      for (int q = 0; q < 4; ++q) {
        if ((nmv.y >> (8 * q)) & 0xFFu) {
          const float obj = (&o1.x)[q];
          const unsigned key = fkey(__float_as_uint(obj));
          const int kb = (int)(key >> 21);
          if (kb > bin1) sgt += softplus_fast(obj);
          else if (kb == bin1) {
            atomicAdd(&hc[(key >> 10) & (NB - 1)], 1u);
            atomicAdd(&hs[(key >> 10) & (NB - 1)], softplus_fast(obj));
          }
        }
      }
    }
    __syncthreads();
    const float t_sgt = blockSum(sgt, fscr);
    unsigned cb2[2]; float sb2[2];
    cb2[0] = hc[2 * t]; cb2[1] = hc[2 * t + 1];
    sb2[0] = hs[2 * t]; sb2[1] = hs[2 * t + 1];
    selectDigit2(cb2, sb2, krem1, t_sgt, iwav, fwav, &sh_dig, &sh_krem, &sh_sa);

    // 13 mantissa bits kept; tie-edge error <= krem2 * width ~ 1e-3, negligible
    const unsigned Tkey = ((unsigned)bin1 << 21) | ((unsigned)sh_dig << 10);
    sel = sh_sa + (float)sh_krem * softplus_fast(__uint_as_float(funkey(Tkey)));
  }

  if (t == 0) {
    const float denom = (float)max(npos, 1);
    atomicAdd(&out[1], (t_po + sel) / denom);
    if (npos > 0) {
      atomicAdd(&out[2], t_ce / denom);
      atomicAdd(&out[3], t_lc / (denom * 4.f));
    }
    __threadfence();
    const unsigned old = atomicAdd(done, 1u);
    if (old == (unsigned)(R - 1)) {          // last row finalizes in place
      const float o = atomicAdd(&out[1], 0.f) * invB;
      const float c = atomicAdd(&out[2], 0.f) * invB;
      const float l = atomicAdd(&out[3], 0.f) * invB;
      out[0] = o + c + l;
      out[1] = o;
      out[2] = c;
      out[3] = l;
    }
  }
}

extern "C" void kernel_launch(void* const* d_in, const int* in_sizes, int n_in,
                              void* d_out, int out_size, void* d_ws, size_t ws_size,
                              hipStream_t stream) {
  (void)n_in; (void)out_size; (void)ws_size;

  const int HW0 = 80 * 80, HW1 = 40 * 40, HW2 = 20 * 20;
  const int B = in_sizes[0] / (NA * KCH * HW0);
  const int R = 3 * B;
  const float invB = 1.f / (float)B;

  ScaleParams p0{(const float*)d_in[0],  (const float*)d_in[1],
                 (const int*)d_in[2],    (const uint8_t*)d_in[3],
                 (const uint8_t*)d_in[4], HW0};
  ScaleParams p1{(const float*)d_in[5],  (const float*)d_in[6],
                 (const int*)d_in[7],    (const uint8_t*)d_in[8],
                 (const uint8_t*)d_in[9], HW1};
  ScaleParams p2{(const float*)d_in[10], (const float*)d_in[11],
                 (const int*)d_in[12],   (const uint8_t*)d_in[13],
                 (const uint8_t*)d_in[14], HW2};

  float* out = (float*)d_out;
  unsigned* done = (unsigned*)d_ws;

  k_zero<<<1, 64, 0, stream>>>(out, done);
  k_row<<<R, BLK, 0, stream>>>(p0, p1, p2, B, R, invB, out, done);
}